// Round 18
// baseline (27.694 us; speedup 1.0000x reference)
//
#include <hip/hip_runtime.h>
#include <hip/hip_fp16.h>
#include <math.h>

#define D 64
#define NC 8
#define FK 8
#define NMIN 1440
#define ITER 4
#define TWO_PI_F 6.28318530717958647692f

#define TSZ ((size_t)NMIN * NC * D)   // table elements

// ---------------------------------------------------------------------------
// Kernel 1: build per-minute Fourier table T[m][n][d], stored as fp16.
// ---------------------------------------------------------------------------
__global__ __launch_bounds__(256) void build_table_kernel(
    const float* __restrict__ a0,
    const float* __restrict__ fa,
    const float* __restrict__ fb,
    __half* __restrict__ T)
{
    const int m = blockIdx.x;
    const int t = threadIdx.x;
    const int d  = t & (D - 1);
    const int n0 = t >> 6;
    const float angle = (float)m * (TWO_PI_F / (float)(NMIN - 1));

    float c[FK], s[FK];
    float s1, c1;
    sincosf(angle, &s1, &c1);
    c[0] = c1; s[0] = s1;
    {
        const float tw = 2.0f * c1;
        float cp = 1.0f, sp = 0.0f;
        float cc = c1, ss = s1;
#pragma unroll
        for (int k = 1; k < FK; ++k) {
            const float cn = fmaf(tw, cc, -cp);
            const float sn = fmaf(tw, ss, -sp);
            cp = cc; sp = ss; cc = cn; ss = sn;
            c[k] = cc; s[k] = ss;
        }
    }

#pragma unroll
    for (int j = 0; j < 2; ++j) {
        const int n = n0 + 4 * j;
        float v = a0[n * D + d];
#pragma unroll
        for (int k = 0; k < FK; ++k) {
            v = fmaf(c[k], fa[(n * FK + k) * D + d], v);
            v = fmaf(s[k], fb[(n * FK + k) * D + d], v);
        }
        T[(size_t)(m * NC + n) * D + d] = __float2half(v);
    }
}

// ---------------------------------------------------------------------------
// 8-lane all-reduce sum on the VALU via DPP (groups are 8-lane aligned).
// ---------------------------------------------------------------------------
__device__ __forceinline__ float grp8_allreduce_sum(float v) {
    int t;
    t = __builtin_amdgcn_update_dpp(0, __float_as_int(v), 0xB1, 0xF, 0xF, true);
    v += __int_as_float(t);
    t = __builtin_amdgcn_update_dpp(0, __float_as_int(v), 0x4E, 0xF, 0xF, true);
    v += __int_as_float(t);
    t = __builtin_amdgcn_update_dpp(0, __float_as_int(v), 0x141, 0xF, 0xF, true);
    v += __int_as_float(t);
    return v;
}

// ---------------------------------------------------------------------------
// Kernel 2: 8 lanes per item, ITER items per group via grid-stride
// (stride chosen so each iteration's accesses are contiguous & coalesced).
// SINGLE CHANGE vs round 17: software pipeline — next item's theta+emb
// loads issued at loop top, hiding the exposed front-of-chain latency.
// proto in LDS; DPP reduce; fp16 T prefetched into regs before softmax.
// ---------------------------------------------------------------------------
__global__ __launch_bounds__(256) void mix_kernel8p(
    const float* __restrict__ emb,
    const float* __restrict__ thetas,
    const float* __restrict__ proto,
    const __half* __restrict__ T,
    float* __restrict__ out_emb,
    float* __restrict__ out_P,
    int B,
    int gstride)           // groups in grid = ceil(B/ITER)
{
    __shared__ float4 sproto[NC * (D / 4)];      // 2 KB
    if (threadIdx.x < NC * (D / 4)) {
        sproto[threadIdx.x] = ((const float4*)proto)[threadIdx.x];
    }
    __syncthreads();

    const int ggid = (blockIdx.x * 256 + threadIdx.x) >> 3;  // global group id
    const int j    = threadIdx.x & 7;                         // lane in group
    if (ggid >= gstride) return;

    int b = ggid;

    // --- iteration-0 front loads ---
    float th = thetas[b];
    const float4* __restrict__ e4 = (const float4*)emb + (size_t)b * (D / 4);
    float4 ev0 = e4[j];
    float4 ev1 = e4[j + 8];

#pragma unroll
    for (int i = 0; i < ITER; ++i) {
        if (b < B) {
            // --- issue NEXT item's front loads first (hidden under this body) ---
            const int bn = b + gstride;
            const bool have_next = (i + 1 < ITER) && (bn < B);
            float th_n = 0.0f;
            float4 en0, en1;
            if (have_next) {
                th_n = thetas[bn];
                const float4* __restrict__ e4n = (const float4*)emb + (size_t)bn * (D / 4);
                en0 = e4n[j];
                en1 = e4n[j + 8];
            }

            // --- minute bucket (th resident since previous iteration) ---
            int m = (int)((th / TWO_PI_F) * (float)NMIN);
            m = m < 0 ? 0 : (m > NMIN - 1 ? NMIN - 1 : m);

            // --- prefetch T rows (consumed after softmax) ---
            const uint2* __restrict__ t2 = (const uint2*)(T + (size_t)m * NC * D);
            uint2 ua[NC], ub[NC];
#pragma unroll
            for (int n = 0; n < NC; ++n) {
                ua[n] = t2[n * 16 + j];
                ub[n] = t2[n * 16 + j + 8];
            }

            // --- partial scores vs 8 prototypes (from LDS) ---
            float sc[NC];
#pragma unroll
            for (int n = 0; n < NC; ++n) {
                const float4 pa = sproto[n * (D / 4) + j];
                const float4 pb = sproto[n * (D / 4) + j + 8];
                float v = ev0.x * pa.x;
                v = fmaf(ev0.y, pa.y, v);
                v = fmaf(ev0.z, pa.z, v);
                v = fmaf(ev0.w, pa.w, v);
                v = fmaf(ev1.x, pb.x, v);
                v = fmaf(ev1.y, pb.y, v);
                v = fmaf(ev1.z, pb.z, v);
                v = fmaf(ev1.w, pb.w, v);
                sc[n] = v;
            }

            // --- reduce across the 8-lane group (VALU/DPP) ---
#pragma unroll
            for (int n = 0; n < NC; ++n) {
                sc[n] = grp8_allreduce_sum(sc[n]);
            }

            // --- softmax(scores / tau), tau = 0.2 -> *5 ---
            float mx = -1e30f;
#pragma unroll
            for (int n = 0; n < NC; ++n) { sc[n] *= 5.0f; mx = fmaxf(mx, sc[n]); }
            float sum = 0.0f;
#pragma unroll
            for (int n = 0; n < NC; ++n) { sc[n] = __expf(sc[n] - mx); sum += sc[n]; }
            const float inv = 1.0f / sum;
#pragma unroll
            for (int n = 0; n < NC; ++n) sc[n] *= inv;

            // --- unpack prefetched T and mix ---
            float4 acc0 = make_float4(0.f, 0.f, 0.f, 0.f);
            float4 acc1 = make_float4(0.f, 0.f, 0.f, 0.f);
#pragma unroll
            for (int n = 0; n < NC; ++n) {
                const float pw = sc[n];
                const float2 a01 = __half22float2(*(const __half2*)&ua[n].x);
                const float2 a23 = __half22float2(*(const __half2*)&ua[n].y);
                const float2 b01 = __half22float2(*(const __half2*)&ub[n].x);
                const float2 b23 = __half22float2(*(const __half2*)&ub[n].y);
                acc0.x = fmaf(pw, a01.x, acc0.x);
                acc0.y = fmaf(pw, a01.y, acc0.y);
                acc0.z = fmaf(pw, a23.x, acc0.z);
                acc0.w = fmaf(pw, a23.y, acc0.w);
                acc1.x = fmaf(pw, b01.x, acc1.x);
                acc1.y = fmaf(pw, b01.y, acc1.y);
                acc1.z = fmaf(pw, b23.x, acc1.z);
                acc1.w = fmaf(pw, b23.y, acc1.w);
            }

            float4* __restrict__ o4 = (float4*)out_emb + (size_t)b * (D / 4);
            o4[j]     = acc0;
            o4[j + 8] = acc1;

            if (j == 0) {
                ((float4*)out_P)[(size_t)b * 2 + 0] = make_float4(sc[0], sc[1], sc[2], sc[3]);
            } else if (j == 4) {
                ((float4*)out_P)[(size_t)b * 2 + 1] = make_float4(sc[4], sc[5], sc[6], sc[7]);
            }

            // --- rotate pipeline ---
            b  = bn;
            th = th_n;
            ev0 = en0;
            ev1 = en1;
        }
    }
}

// ---------------------------------------------------------------------------
// Fallback (only if ws_size too small): fully fused, coefficients in LDS.
// ---------------------------------------------------------------------------
__global__ __launch_bounds__(256) void fused_fallback(
    const float* __restrict__ emb,
    const float* __restrict__ thetas,
    const float* __restrict__ proto,
    const float* __restrict__ a0,
    const float* __restrict__ fa,
    const float* __restrict__ fb,
    float* __restrict__ out_emb,
    float* __restrict__ out_P,
    int B)
{
    __shared__ float sp[NC * D];
    __shared__ float sa0[NC * D];
    __shared__ float sfa[NC * FK * D];
    __shared__ float sfb[NC * FK * D];
    for (int i = threadIdx.x; i < NC * D; i += 256) { sp[i] = proto[i]; sa0[i] = a0[i]; }
    for (int i = threadIdx.x; i < NC * FK * D; i += 256) { sfa[i] = fa[i]; sfb[i] = fb[i]; }
    __syncthreads();

    const int b = blockIdx.x * 256 + threadIdx.x;
    if (b >= B) return;

    const float4* __restrict__ e4  = (const float4*)(emb + (size_t)b * D);
    const float4* sp4  = (const float4*)sp;
    const float4* sa04 = (const float4*)sa0;
    const float4* sfa4 = (const float4*)sfa;
    const float4* sfb4 = (const float4*)sfb;

    float sc[NC];
#pragma unroll
    for (int n = 0; n < NC; ++n) sc[n] = 0.0f;
#pragma unroll
    for (int i = 0; i < D / 4; ++i) {
        const float4 ev = e4[i];
#pragma unroll
        for (int n = 0; n < NC; ++n) {
            const float4 pv = sp4[n * (D / 4) + i];
            sc[n] = fmaf(ev.x, pv.x, sc[n]);
            sc[n] = fmaf(ev.y, pv.y, sc[n]);
            sc[n] = fmaf(ev.z, pv.z, sc[n]);
            sc[n] = fmaf(ev.w, pv.w, sc[n]);
        }
    }
    float mx = -1e30f;
#pragma unroll
    for (int n = 0; n < NC; ++n) { sc[n] *= 5.0f; mx = fmaxf(mx, sc[n]); }
    float sum = 0.0f;
#pragma unroll
    for (int n = 0; n < NC; ++n) { sc[n] = __expf(sc[n] - mx); sum += sc[n]; }
    const float inv = 1.0f / sum;
#pragma unroll
    for (int n = 0; n < NC; ++n) sc[n] *= inv;

    const float th = thetas[b];
    int m = (int)((th / TWO_PI_F) * (float)NMIN);
    m = m < 0 ? 0 : (m > NMIN - 1 ? NMIN - 1 : m);
    const float angle = (float)m * (TWO_PI_F / (float)(NMIN - 1));
    float c[FK], s[FK];
#pragma unroll
    for (int k = 0; k < FK; ++k) sincosf(angle * (float)(k + 1), &s[k], &c[k]);

    float4 acc[D / 4];
#pragma unroll
    for (int i = 0; i < D / 4; ++i) acc[i] = make_float4(0.f, 0.f, 0.f, 0.f);
#pragma unroll
    for (int n = 0; n < NC; ++n) {
        const float pw = sc[n];
#pragma unroll
        for (int i = 0; i < D / 4; ++i) {
            float4 v = sa04[n * (D / 4) + i];
#pragma unroll
            for (int k = 0; k < FK; ++k) {
                const float4 av = sfa4[(n * FK + k) * (D / 4) + i];
                const float4 bv = sfb4[(n * FK + k) * (D / 4) + i];
                v.x = fmaf(c[k], av.x, v.x); v.x = fmaf(s[k], bv.x, v.x);
                v.y = fmaf(c[k], av.y, v.y); v.y = fmaf(s[k], bv.y, v.y);
                v.z = fmaf(c[k], av.z, v.z); v.z = fmaf(s[k], bv.z, v.z);
                v.w = fmaf(c[k], av.w, v.w); v.w = fmaf(s[k], bv.w, v.w);
            }
            acc[i].x = fmaf(pw, v.x, acc[i].x);
            acc[i].y = fmaf(pw, v.y, acc[i].y);
            acc[i].z = fmaf(pw, v.z, acc[i].z);
            acc[i].w = fmaf(pw, v.w, acc[i].w);
        }
    }
    float4* o4 = (float4*)(out_emb + (size_t)b * D);
#pragma unroll
    for (int i = 0; i < D / 4; ++i) o4[i] = acc[i];
    float4* op = (float4*)(out_P + (size_t)b * NC);
    op[0] = make_float4(sc[0], sc[1], sc[2], sc[3]);
    op[1] = make_float4(sc[4], sc[5], sc[6], sc[7]);
}

extern "C" void kernel_launch(void* const* d_in, const int* in_sizes, int n_in,
                              void* d_out, int out_size, void* d_ws, size_t ws_size,
                              hipStream_t stream)
{
    const float* emb    = (const float*)d_in[0];
    const float* thetas = (const float*)d_in[1];
    const float* proto  = (const float*)d_in[2];
    const float* a0     = (const float*)d_in[3];
    const float* fa     = (const float*)d_in[4];
    const float* fb     = (const float*)d_in[5];

    const int B = in_sizes[0] / D;           // 131072
    float* out_emb = (float*)d_out;
    float* out_P   = (float*)d_out + (size_t)B * D;

    const size_t table_bytes = TSZ * sizeof(__half);   // ~1.5 MB

    if (ws_size >= table_bytes) {
        __half* T = (__half*)d_ws;
        build_table_kernel<<<NMIN, 256, 0, stream>>>(a0, fa, fb, T);
        // ITER items per 8-lane group: groups = ceil(B/ITER)
        const int gstride = (B + ITER - 1) / ITER;            // 32768
        const long long total_threads = (long long)gstride * 8;
        const int blocks = (int)((total_threads + 255) / 256); // 1024
        mix_kernel8p<<<blocks, 256, 0, stream>>>(emb, thetas, proto, T,
                                                 out_emb, out_P, B, gstride);
    } else {
        const int blocks = (B + 255) / 256;
        fused_fallback<<<blocks, 256, 0, stream>>>(emb, thetas, proto, a0, fa, fb,
                                                   out_emb, out_P, B);
    }
}